// Round 9
// baseline (144.337 us; speedup 1.0000x reference)
//
#include <hip/hip_runtime.h>

// Problem constants
constexpr int cB = 64, cS = 512, cN = 512, cM = 128, cUNF = 6;
constexpr float cDELTA = 0.016666666666666666f;  // DT/UNFOLDS = 0.1/6

// Decomposition: 16 batch-groups (KB=4) x 16 j-tiles (JT=32) = 256 blocks, 1024 thr.
constexpr int KB = 4;
constexpr int JT = 32;
constexpr int NJT = cN / JT;          // 16
constexpr int NT = 1024;
constexpr int NW = NT / 64;           // 16 waves
constexpr int NB = (cB / KB) * NJT;   // 256

// k_main unfold-loop layout: thread owns 2 consecutive j, 8 i per chunk.
constexpr int ILEN = 8;               // i per thread
// k_prep sensory layout: 1 j per thread, 16 s per chunk.
constexpr int SLEN = 16;

// Dynamic LDS (k_main), float offsets:
constexpr int SM_EW    = 0;                        // float2[512*32] = 128 KB
constexpr int SM_STAGE = cN * JT * 2;              // 32768: float[2048] = 8 KB
constexpr int SM_REDR  = SM_STAGE + cN * KB;       // 34816: float[2048] = 8 KB
constexpr int SM_REDW  = SM_REDR + KB * NW * JT;   // 36864: float[2048] = 8 KB
constexpr int SM_FLOATS = SM_REDW + KB * NW * JT;  // 38912
constexpr size_t SMEM_BYTES = (size_t)SM_FLOATS * 4;  // 155648 B

// ws layout (float offsets)
constexpr size_t OFF_EWT = 0;                            // float2[N*N], jt-tiled
constexpr size_t OFF_SRB = (size_t)cN * cN * 2;          // [B*N] s_rev + bias
constexpr size_t OFF_SW  = OFF_SRB + (size_t)cB * cN;    // [B*N] s_w
constexpr size_t OFF_VA  = OFF_SW  + (size_t)cB * cN;    // [B*N] v ping
constexpr size_t OFF_VB  = OFF_VA  + (size_t)cB * cN;    // [B*N] v pong
constexpr size_t OFF_CTR = OFF_VB  + (size_t)cB * cN;    // ints: [bg*16] barriers, [256+jt] flags
constexpr int CTR_INTS = 256 + 16;

__device__ __forceinline__ float clamp01(float x) {
    return __builtin_amdgcn_fmed3f(x, 0.0f, 1.0f);
}

// ---- k_prep: EW tiled pack + uniformity probe + sensory reduction ----
__global__ __launch_bounds__(NT)
void k_prep(const float* __restrict__ inputs, const float* __restrict__ bias,
            const float* __restrict__ erev,  const float* __restrict__ wgt,
            const float* __restrict__ sigma, const float* __restrict__ mu,
            const float* __restrict__ serev, const float* __restrict__ swgt,
            const float* __restrict__ ssigma,const float* __restrict__ smu,
            const float* __restrict__ mask,  const float* __restrict__ smask,
            const float* __restrict__ inw,   const float* __restrict__ inb,
            float* __restrict__ ws)
{
    float2* EWt  = (float2*)(ws + OFF_EWT);
    float*  srb  = ws + OFF_SRB;
    float*  swS  = ws + OFF_SW;
    int*    ctr  = (int*)(ws + OFF_CTR);
    int*    flags = ctr + 256;

    const int tid = threadIdx.x, bid = blockIdx.x;
    const int bg = bid >> 4, jt = bid & (NJT - 1);
    const int b0 = bg * KB, j0 = jt * JT;
    const int jl = tid & (JT - 1), ic = tid >> 5;
    const int wv_id = tid >> 6, lane = tid & 63;
    const int j = j0 + jl;

    __shared__ float xsh[cS * KB];        // 8 KB
    __shared__ float redR[KB * NW * JT];  // 8 KB
    __shared__ float redW[KB * NW * JT];  // 8 KB

    // EW pack (tiled) + probe: one element per thread (256*1024 == 512*512)
    {
        int idx = bid * NT + tid;
        int i = idx >> 9, jj = idx & (cN - 1);
        int jtt = jj >> 5, jjl = jj & (JT - 1);
        float mk = mask[idx];
        EWt[(size_t)jtt * (cN * JT) + i * JT + jjl] =
            make_float2(erev[idx] * mk, wgt[idx] * mk);
        // gate generality only matters where mask != 0
        if (mk != 0.0f && !((sigma[idx] == 0.5f) && (mu[idx] == 0.5f)))
            atomicOr(&flags[jtt], 1);
    }

    // stage x[b][s] as xsh[s*4+b]
#pragma unroll
    for (int r = 0; r < (cS * KB) / NT; ++r) {
        int t = tid + r * NT;
        int bb = t & 3, s = t >> 2;
        xsh[t] = fmaf(inputs[(b0 + bb) * cS + s], inw[s], inb[s]);
    }
    __syncthreads();

    // sensory reduction (1 j/thread, SLEN s per chunk)
    {
        float aR[KB] = {0.f, 0.f, 0.f, 0.f}, aW[KB] = {0.f, 0.f, 0.f, 0.f};
        int idx = (ic * SLEN) * cN + j;
        int xo  = (ic * SLEN) * KB;
#pragma unroll 4
        for (int ii = 0; ii < SLEN; ++ii, idx += cN, xo += KB) {
            float sg = ssigma[idx];
            float a  = 0.5f / sg;
            float c  = fmaf(-smu[idx], a, 0.5f);
            float mk = smask[idx];
            float e  = serev[idx] * mk;
            float wv = swgt[idx] * mk;
            const float4 xv = *(const float4*)&xsh[xo];
            float g;
            g = clamp01(fmaf(xv.x, a, c)); aR[0] = fmaf(g, e, aR[0]); aW[0] = fmaf(g, wv, aW[0]);
            g = clamp01(fmaf(xv.y, a, c)); aR[1] = fmaf(g, e, aR[1]); aW[1] = fmaf(g, wv, aW[1]);
            g = clamp01(fmaf(xv.z, a, c)); aR[2] = fmaf(g, e, aR[2]); aW[2] = fmaf(g, wv, aW[2]);
            g = clamp01(fmaf(xv.w, a, c)); aR[3] = fmaf(g, e, aR[3]); aW[3] = fmaf(g, wv, aW[3]);
        }
        // wave pre-reduce: combine the wave's two s-chunks (lanes ^32)
#pragma unroll
        for (int b = 0; b < KB; ++b) {
            aR[b] += __shfl_xor(aR[b], 32, 64);
            aW[b] += __shfl_xor(aW[b], 32, 64);
        }
        if (lane < JT) {
#pragma unroll
            for (int b = 0; b < KB; ++b) {
                redR[(b * NW + wv_id) * JT + jl] = aR[b];
                redW[(b * NW + wv_id) * JT + jl] = aW[b];
            }
        }
    }
    __syncthreads();

    if (tid < JT * KB) {
        int jj = tid & (JT - 1), bb = tid >> 5;
        float r = 0.f, wv = 0.f;
#pragma unroll
        for (int w = 0; w < NW; ++w) {
            r  += redR[(bb * NW + w) * JT + jj];
            wv += redW[(bb * NW + w) * JT + jj];
        }
        int jg = j0 + jj;
        int gidx = (b0 + bb) * cN + jg;
        srb[gidx] = r + bias[jg];   // s_rev + b folded
        swS[gidx] = wv;
    }
}

// ---- k_main: linear 128KB EW copy -> LDS (minimal live regs: NO register
//      staging, the r8 spill lesson), then 6 unfolds. Thread owns 2
//      consecutive j (1 b128 = {e,w}x2j per iter), 8 i/chunk. v exchanged
//      via sc1 atomics; per-bg 16-way relaxed barriers. ----
__global__ __launch_bounds__(NT)
void k_main(const float* __restrict__ states, const float* __restrict__ tau,
            const float* __restrict__ sigma,  const float* __restrict__ mu,
            const float* __restrict__ outw,   const float* __restrict__ outb,
            float* __restrict__ out, float* __restrict__ ws)
{
    extern __shared__ float smem[];
    float*  ewlf  = smem + SM_EW;         // float2 slice
    float*  stage = smem + SM_STAGE;
    float*  redR  = smem + SM_REDR;
    float*  redW  = smem + SM_REDW;

    const float* srb = ws + OFF_SRB;
    const float* swS = ws + OFF_SW;
    float* vA  = ws + OFF_VA;
    float* vB  = ws + OFF_VB;
    int*   ctr = (int*)(ws + OFF_CTR);

    const int tid = threadIdx.x, bid = blockIdx.x;
    // XCD swizzle: 16 blocks sharing a jt have bid%8 const -> same XCD L2.
    const int jt = (bid & 7) * 2 + ((bid >> 3) & 1);
    const int bg = bid >> 4;
    const int b0 = bg * KB, j0 = jt * JT;
    const int jp = tid & 15;             // j-pair: j = j0 + 2*jp, +1
    const int ic = tid >> 4;             // 0..63, i = ic*8 + ii
    const int wv_id = tid >> 6, lane = tid & 63;
    int* barU  = ctr + bg * 16;
    const int* flags = ctr + 256;

    // ---- EW slice: linear 128 KB copy, at most 2 float4 in flight ----
    {
        const float4* gsrc = (const float4*)(ws + OFF_EWT) + (size_t)jt * (cN * JT / 2);
        float4* ldst = (float4*)ewlf;
#pragma unroll 2
        for (int k = 0; k < 8; ++k)
            ldst[k * NT + tid] = gsrc[k * NT + tid];
    }
    const int fast = (flags[jt] == 0);

    // owner threads (tid < 128) own (bb, jj); prefetch epilogue scalars
    float my_srb = 0.f, my_sw = 0.f, my_tau = 0.f, my_ow = 0.f, my_ob = 0.f;
    int my_gidx = 0, my_mi = -1;
    if (tid < JT * KB) {
        int jj = tid & (JT - 1), bb = tid >> 5;
        int jg = j0 + jj;
        my_gidx = (b0 + bb) * cN + jg;
        my_srb  = srb[my_gidx];
        my_sw   = swS[my_gidx];
        my_tau  = tau[jg];
        if (jg >= cN - cM) {
            int m = jg - (cN - cM);
            my_ow = outw[m]; my_ob = outb[m];
            my_mi = (b0 + bb) * cM + m;
        }
    }

    // ---- 6 unfolds ----
    const float* vin = states;
    for (int u = 0; u < cUNF; ++u) {
        float* vout = (u == cUNF - 1) ? (out + cB * cM) : ((u & 1) ? vA : vB);

        // stage v (sc1 loads: always-fresh, bypass stale per-XCD L2)
#pragma unroll
        for (int r = 0; r < (cN * KB) / NT; ++r) {   // 2 per thread
            int t = tid + r * NT;
            int bb = t & 3, ii = t >> 2;
            float vvv = __hip_atomic_load(&vin[(b0 + bb) * cN + ii],
                                          __ATOMIC_RELAXED, __HIP_MEMORY_SCOPE_AGENT);
            stage[t] = fast ? clamp01(vvv) : vvv;
        }
        __syncthreads();

        float vold = 0.f;
        if (tid < JT * KB)
            vold = __hip_atomic_load(&vin[my_gidx],
                                     __ATOMIC_RELAXED, __HIP_MEMORY_SCOPE_AGENT);

        // accumulators: [even j][b], [odd j][b] for R and W
        float aR0[KB] = {0,0,0,0}, aW0[KB] = {0,0,0,0};
        float aR1[KB] = {0,0,0,0}, aW1[KB] = {0,0,0,0};
        const float4* ew4 = (const float4*)ewlf;   // index i*16 + jp
        if (fast) {
#pragma unroll
            for (int ii = 0; ii < ILEN; ++ii) {
                int i = ic * ILEN + ii;
                const float4 ew = ew4[i * 16 + jp];          // {e0,w0,e1,w1}
                const float4 g4 = *(const float4*)&stage[i * KB];
                aR0[0] = fmaf(g4.x, ew.x, aR0[0]); aW0[0] = fmaf(g4.x, ew.y, aW0[0]);
                aR0[1] = fmaf(g4.y, ew.x, aR0[1]); aW0[1] = fmaf(g4.y, ew.y, aW0[1]);
                aR0[2] = fmaf(g4.z, ew.x, aR0[2]); aW0[2] = fmaf(g4.z, ew.y, aW0[2]);
                aR0[3] = fmaf(g4.w, ew.x, aR0[3]); aW0[3] = fmaf(g4.w, ew.y, aW0[3]);
                aR1[0] = fmaf(g4.x, ew.z, aR1[0]); aW1[0] = fmaf(g4.x, ew.w, aW1[0]);
                aR1[1] = fmaf(g4.y, ew.z, aR1[1]); aW1[1] = fmaf(g4.y, ew.w, aW1[1]);
                aR1[2] = fmaf(g4.z, ew.z, aR1[2]); aW1[2] = fmaf(g4.z, ew.w, aW1[2]);
                aR1[3] = fmaf(g4.w, ew.z, aR1[3]); aW1[3] = fmaf(g4.w, ew.w, aW1[3]);
            }
        } else {
            int j2 = j0 + jp * 2;
#pragma unroll 2
            for (int ii = 0; ii < ILEN; ++ii) {
                int i = ic * ILEN + ii;
                const float4 ew = ew4[i * 16 + jp];
                float sg0 = sigma[i * cN + j2],     mu0 = mu[i * cN + j2];
                float sg1 = sigma[i * cN + j2 + 1], mu1 = mu[i * cN + j2 + 1];
                float a0 = 0.5f / sg0, c0 = fmaf(-mu0, a0, 0.5f);
                float a1 = 0.5f / sg1, c1 = fmaf(-mu1, a1, 0.5f);
                const float4 v4 = *(const float4*)&stage[i * KB];
                float g;
                g = clamp01(fmaf(v4.x, a0, c0)); aR0[0] = fmaf(g, ew.x, aR0[0]); aW0[0] = fmaf(g, ew.y, aW0[0]);
                g = clamp01(fmaf(v4.y, a0, c0)); aR0[1] = fmaf(g, ew.x, aR0[1]); aW0[1] = fmaf(g, ew.y, aW0[1]);
                g = clamp01(fmaf(v4.z, a0, c0)); aR0[2] = fmaf(g, ew.x, aR0[2]); aW0[2] = fmaf(g, ew.y, aW0[2]);
                g = clamp01(fmaf(v4.w, a0, c0)); aR0[3] = fmaf(g, ew.x, aR0[3]); aW0[3] = fmaf(g, ew.y, aW0[3]);
                g = clamp01(fmaf(v4.x, a1, c1)); aR1[0] = fmaf(g, ew.z, aR1[0]); aW1[0] = fmaf(g, ew.w, aW1[0]);
                g = clamp01(fmaf(v4.y, a1, c1)); aR1[1] = fmaf(g, ew.z, aR1[1]); aW1[1] = fmaf(g, ew.w, aW1[1]);
                g = clamp01(fmaf(v4.z, a1, c1)); aR1[2] = fmaf(g, ew.z, aR1[2]); aW1[2] = fmaf(g, ew.w, aW1[2]);
                g = clamp01(fmaf(v4.w, a1, c1)); aR1[3] = fmaf(g, ew.z, aR1[3]); aW1[3] = fmaf(g, ew.w, aW1[3]);
            }
        }
        // wave reduce over the wave's 4 ic-parts (lane bits 4,5)
#pragma unroll
        for (int b = 0; b < KB; ++b) {
            aR0[b] += __shfl_xor(aR0[b], 16, 64); aR0[b] += __shfl_xor(aR0[b], 32, 64);
            aW0[b] += __shfl_xor(aW0[b], 16, 64); aW0[b] += __shfl_xor(aW0[b], 32, 64);
            aR1[b] += __shfl_xor(aR1[b], 16, 64); aR1[b] += __shfl_xor(aR1[b], 32, 64);
            aW1[b] += __shfl_xor(aW1[b], 16, 64); aW1[b] += __shfl_xor(aW1[b], 32, 64);
        }
        if (lane < 16) {
#pragma unroll
            for (int b = 0; b < KB; ++b) {
                *(float2*)&redR[(b * NW + wv_id) * JT + lane * 2] = make_float2(aR0[b], aR1[b]);
                *(float2*)&redW[(b * NW + wv_id) * JT + lane * 2] = make_float2(aW0[b], aW1[b]);
            }
        }
        __syncthreads();

        if (tid < JT * KB) {
            int jj = tid & (JT - 1), bb = tid >> 5;
            float r = 0.f, wv = 0.f;
#pragma unroll
            for (int w = 0; w < NW; ++w) {
                r  += redR[(bb * NW + w) * JT + jj];
                wv += redW[(bb * NW + w) * JT + jj];
            }
            r  += my_srb;
            wv += my_sw;
            float k    = 1.0f / (1.0f + wv);
            float taun = my_tau * k;
            float inv  = 1.0f / (taun + cDELTA);
            float vn   = (taun * inv) * vold + (cDELTA * inv) * k * r;
            if (u == cUNF - 1) {
                vout[my_gidx] = vn;                       // plain: dispatch-end flush
                if (my_mi >= 0) out[my_mi] = fmaf(vn, my_ow, my_ob);
            } else {
                __hip_atomic_store(&vout[my_gidx], vn,
                                   __ATOMIC_RELAXED, __HIP_MEMORY_SCOPE_AGENT);
            }
        }

        if (u < cUNF - 1) {
            __syncthreads();   // vmcnt(0) drain: block's sc1 v-stores at coherence point
            if (tid == 0) {
                __hip_atomic_fetch_add(barU, 1, __ATOMIC_RELAXED, __HIP_MEMORY_SCOPE_AGENT);
                const int target = NJT * (u + 1);   // monotonic counter
                while (__hip_atomic_load(barU, __ATOMIC_RELAXED, __HIP_MEMORY_SCOPE_AGENT) < target)
                    __builtin_amdgcn_s_sleep(1);
            }
            __syncthreads();
            vin = (u & 1) ? vA : vB;   // buffer just produced
        }
    }
}

extern "C" void kernel_launch(void* const* d_in, const int* in_sizes, int n_in,
                              void* d_out, int out_size, void* d_ws, size_t ws_size,
                              hipStream_t stream)
{
    const float* inputs = (const float*)d_in[0];
    const float* states = (const float*)d_in[1];
    const float* tau    = (const float*)d_in[2];
    const float* bias   = (const float*)d_in[3];
    const float* erev   = (const float*)d_in[4];
    const float* wgt    = (const float*)d_in[5];
    const float* sigma  = (const float*)d_in[6];
    const float* mu     = (const float*)d_in[7];
    const float* serev  = (const float*)d_in[8];
    const float* swgt   = (const float*)d_in[9];
    const float* ssigma = (const float*)d_in[10];
    const float* smu    = (const float*)d_in[11];
    const float* mask   = (const float*)d_in[12];
    const float* smask  = (const float*)d_in[13];
    const float* inw    = (const float*)d_in[14];
    const float* inb    = (const float*)d_in[15];
    const float* outw   = (const float*)d_in[16];
    const float* outb   = (const float*)d_in[17];
    float* out = (float*)d_out;
    float* ws  = (float*)d_ws;

    hipFuncSetAttribute((const void*)k_main,
                        hipFuncAttributeMaxDynamicSharedMemorySize,
                        (int)SMEM_BYTES);

    // zero barrier counters + flags
    hipMemsetAsync(ws + OFF_CTR, 0, CTR_INTS * sizeof(int), stream);

    k_prep<<<NB, NT, 0, stream>>>(inputs, bias, erev, wgt, sigma, mu,
                                  serev, swgt, ssigma, smu, mask, smask,
                                  inw, inb, ws);

    // 256 blocks x 1024 threads = 1 block/CU, all co-resident -> internal
    // spin barriers cannot deadlock.
    k_main<<<NB, NT, SMEM_BYTES, stream>>>(states, tau, sigma, mu,
                                           outw, outb, out, ws);
}

// Round 10
// 127.519 us; speedup vs baseline: 1.1319x; 1.1319x over previous
//
#include <hip/hip_runtime.h>
#include <string.h>

// Problem constants
constexpr int cB = 64, cS = 512, cN = 512, cM = 128, cUNF = 6;
constexpr float cDELTA = 0.016666666666666666f;  // DT/UNFOLDS = 0.1/6

// Decomposition: 16 batch-groups (KB=4) x 16 j-tiles (JT=32) = 256 blocks, 1024 thr.
// Thread layout (k_main + k_prep reductions): jl = tid&31 (j lane), ic = tid>>5
// (i-chunk 0..31), ILEN=16 i per thread -- the r3-proven shape (VGPR 52, no spill).
constexpr int KB = 4;
constexpr int JT = 32;
constexpr int NJT = cN / JT;          // 16
constexpr int NT = 1024;
constexpr int NW = NT / 64;           // 16 waves
constexpr int NB = (cB / KB) * NJT;   // 256
constexpr int ILEN = 16;              // i per thread (k_main)
constexpr int SLEN = 16;              // s per thread (k_prep)

// ws layout (float offsets)
constexpr size_t OFF_EWT = 0;                            // float2[N*N], jt-tiled [jt][i][jl]
constexpr size_t OFF_SRB = (size_t)cN * cN * 2;          // [B*N] s_rev + bias
constexpr size_t OFF_SW  = OFF_SRB + (size_t)cB * cN;    // [B*N] s_w
constexpr size_t OFF_VA  = OFF_SW  + (size_t)cB * cN;    // [B*N] v ping
constexpr size_t OFF_VB  = OFF_VA  + (size_t)cB * cN;    // [B*N] v pong
constexpr size_t OFF_CTR = OFF_VB  + (size_t)cB * cN;    // ints: [bg*16] barriers, [256+jt] flags
constexpr int CTR_INTS = 256 + 16;

__device__ __forceinline__ float clamp01(float x) {
    return __builtin_amdgcn_fmed3f(x, 0.0f, 1.0f);
}

// ---- k_prep: EW tiled pack (sc1 -> L3) + uniformity probe + sensory reduction ----
__global__ __launch_bounds__(NT)
void k_prep(const float* __restrict__ inputs, const float* __restrict__ bias,
            const float* __restrict__ erev,  const float* __restrict__ wgt,
            const float* __restrict__ sigma, const float* __restrict__ mu,
            const float* __restrict__ serev, const float* __restrict__ swgt,
            const float* __restrict__ ssigma,const float* __restrict__ smu,
            const float* __restrict__ mask,  const float* __restrict__ smask,
            const float* __restrict__ inw,   const float* __restrict__ inb,
            float* __restrict__ ws)
{
    float2* EWt  = (float2*)(ws + OFF_EWT);
    float*  srb  = ws + OFF_SRB;
    float*  swS  = ws + OFF_SW;
    int*    ctr  = (int*)(ws + OFF_CTR);
    int*    flags = ctr + 256;

    const int tid = threadIdx.x, bid = blockIdx.x;
    const int bg = bid >> 4, jt = bid & (NJT - 1);
    const int b0 = bg * KB, j0 = jt * JT;
    const int jl = tid & (JT - 1), ic = tid >> 5;
    const int wv_id = tid >> 6, lane = tid & 63;
    const int j = j0 + jl;

    __shared__ float xsh[cS * KB];        // 8 KB
    __shared__ float redR[KB * NW * JT];  // 8 KB
    __shared__ float redW[KB * NW * JT];  // 8 KB

    // EW pack (tiled) + probe: one element per thread (256*1024 == 512*512).
    // sc1 store -> lands at the coherence point (L3): k_main's reads are
    // L3-served instead of round-tripping through HBM after the L2 flush.
    {
        int idx = bid * NT + tid;
        int i = idx >> 9, jj = idx & (cN - 1);
        int jtt = jj >> 5, jjl = jj & (JT - 1);
        float mk = mask[idx];
        float2 ew = make_float2(erev[idx] * mk, wgt[idx] * mk);
        unsigned long long bits;
        memcpy(&bits, &ew, 8);
        __hip_atomic_store(
            (unsigned long long*)&EWt[(size_t)jtt * (cN * JT) + i * JT + jjl],
            bits, __ATOMIC_RELAXED, __HIP_MEMORY_SCOPE_AGENT);
        // gate generality only matters where mask != 0
        if (mk != 0.0f && !((sigma[idx] == 0.5f) && (mu[idx] == 0.5f)))
            atomicOr(&flags[jtt], 1);
    }

    // stage x[b][s] as xsh[s*4+b]
#pragma unroll
    for (int r = 0; r < (cS * KB) / NT; ++r) {
        int t = tid + r * NT;
        int bb = t & 3, s = t >> 2;
        xsh[t] = fmaf(inputs[(b0 + bb) * cS + s], inw[s], inb[s]);
    }
    __syncthreads();

    // sensory reduction (1 j/thread, SLEN s per chunk)
    {
        float aR[KB] = {0.f, 0.f, 0.f, 0.f}, aW[KB] = {0.f, 0.f, 0.f, 0.f};
        int idx = (ic * SLEN) * cN + j;
        int xo  = (ic * SLEN) * KB;
#pragma unroll 4
        for (int ii = 0; ii < SLEN; ++ii, idx += cN, xo += KB) {
            float sg = ssigma[idx];
            float a  = 0.5f / sg;
            float c  = fmaf(-smu[idx], a, 0.5f);
            float mk = smask[idx];
            float e  = serev[idx] * mk;
            float wv = swgt[idx] * mk;
            const float4 xv = *(const float4*)&xsh[xo];
            float g;
            g = clamp01(fmaf(xv.x, a, c)); aR[0] = fmaf(g, e, aR[0]); aW[0] = fmaf(g, wv, aW[0]);
            g = clamp01(fmaf(xv.y, a, c)); aR[1] = fmaf(g, e, aR[1]); aW[1] = fmaf(g, wv, aW[1]);
            g = clamp01(fmaf(xv.z, a, c)); aR[2] = fmaf(g, e, aR[2]); aW[2] = fmaf(g, wv, aW[2]);
            g = clamp01(fmaf(xv.w, a, c)); aR[3] = fmaf(g, e, aR[3]); aW[3] = fmaf(g, wv, aW[3]);
        }
        // wave pre-reduce: combine the wave's two s-chunks (lanes ^32)
#pragma unroll
        for (int b = 0; b < KB; ++b) {
            aR[b] += __shfl_xor(aR[b], 32, 64);
            aW[b] += __shfl_xor(aW[b], 32, 64);
        }
        if (lane < JT) {
#pragma unroll
            for (int b = 0; b < KB; ++b) {
                redR[(b * NW + wv_id) * JT + lane] = aR[b];
                redW[(b * NW + wv_id) * JT + lane] = aW[b];
            }
        }
    }
    __syncthreads();

    if (tid < JT * KB) {
        int jj = tid & (JT - 1), bb = tid >> 5;
        float r = 0.f, wv = 0.f;
#pragma unroll
        for (int w = 0; w < NW; ++w) {
            r  += redR[(bb * NW + w) * JT + jj];
            wv += redW[(bb * NW + w) * JT + jj];
        }
        int jg = j0 + jj;
        int gidx = (b0 + bb) * cN + jg;
        srb[gidx] = r + bias[jg];   // s_rev + b folded
        swS[gidx] = wv;
    }
}

// ---- k_main: the r3-proven unfold body (1 j/thread, 8 accumulators, EW
//      float2 re-read from the tiled global image each unfold -- L2/L3
//      served) + r5's per-bg relaxed barriers + sc1 v exchange. No large
//      LDS, no per-thread param arrays, no register staging. ----
__global__ __launch_bounds__(NT, 4)
void k_main(const float* __restrict__ states, const float* __restrict__ tau,
            const float* __restrict__ sigma,  const float* __restrict__ mu,
            const float* __restrict__ outw,   const float* __restrict__ outb,
            float* __restrict__ out, float* __restrict__ ws)
{
    const float* srb = ws + OFF_SRB;
    const float* swS = ws + OFF_SW;
    float* vA  = ws + OFF_VA;
    float* vB  = ws + OFF_VB;
    int*   ctr = (int*)(ws + OFF_CTR);

    const int tid = threadIdx.x, bid = blockIdx.x;
    // XCD swizzle: 16 blocks sharing a jt have bid%8 const -> same XCD, so
    // the 128 KB EWt slice is L2-resident for all of them after unfold 0.
    const int jt = (bid & 7) * 2 + ((bid >> 3) & 1);
    const int bg = bid >> 4;
    const int b0 = bg * KB, j0 = jt * JT;
    const int jl = tid & (JT - 1), ic = tid >> 5;
    const int wv_id = tid >> 6, lane = tid & 63;
    int* barU = ctr + bg * 16;           // per-bg 64B-spaced barrier line
    const int* flags = ctr + 256;

    const float2* ews = (const float2*)(ws + OFF_EWT) + (size_t)jt * (cN * JT);

    __shared__ float stage[cN * KB];      // 8 KB, v staging [i*4+b]
    __shared__ float redR[KB * NW * JT];  // 8 KB
    __shared__ float redW[KB * NW * JT];  // 8 KB

    const int fast = (flags[jt] == 0);

    // owner threads (tid < 128) own (bb, jj); prefetch epilogue scalars
    float my_srb = 0.f, my_sw = 0.f, my_tau = 0.f, my_ow = 0.f, my_ob = 0.f;
    int my_gidx = 0, my_mi = -1;
    if (tid < JT * KB) {
        int jj = tid & (JT - 1), bb = tid >> 5;
        int jg = j0 + jj;
        my_gidx = (b0 + bb) * cN + jg;
        my_srb  = srb[my_gidx];
        my_sw   = swS[my_gidx];
        my_tau  = tau[jg];
        if (jg >= cN - cM) {
            int m = jg - (cN - cM);
            my_ow = outw[m]; my_ob = outb[m];
            my_mi = (b0 + bb) * cM + m;
        }
    }

    // ---- 6 unfolds ----
    const float* vin = states;
    for (int u = 0; u < cUNF; ++u) {
        float* vout = (u == cUNF - 1) ? (out + cB * cM) : ((u & 1) ? vA : vB);

        // stage v (sc1 loads: always-fresh, bypass stale per-XCD L2)
#pragma unroll
        for (int r = 0; r < (cN * KB) / NT; ++r) {   // 2 per thread
            int t = tid + r * NT;
            int bb = t & 3, ii = t >> 2;
            float vvv = __hip_atomic_load(&vin[(b0 + bb) * cN + ii],
                                          __ATOMIC_RELAXED, __HIP_MEMORY_SCOPE_AGENT);
            stage[t] = fast ? clamp01(vvv) : vvv;
        }
        __syncthreads();

        float vold = 0.f;
        if (tid < JT * KB)
            vold = __hip_atomic_load(&vin[my_gidx],
                                     __ATOMIC_RELAXED, __HIP_MEMORY_SCOPE_AGENT);

        float aR[KB] = {0.f, 0.f, 0.f, 0.f}, aW[KB] = {0.f, 0.f, 0.f, 0.f};
        if (fast) {
            // gate applied at staging: coalesced float2 EW (L2-hot) +
            // ds_read_b128 v broadcast + 8 fma per i
            int eo = (ic * ILEN) * JT + jl;
            int vo = (ic * ILEN) * KB;
#pragma unroll 8
            for (int ii = 0; ii < ILEN; ++ii, eo += JT, vo += KB) {
                const float2 ew = ews[eo];
                const float4 g4 = *(const float4*)&stage[vo];
                aR[0] = fmaf(g4.x, ew.x, aR[0]); aW[0] = fmaf(g4.x, ew.y, aW[0]);
                aR[1] = fmaf(g4.y, ew.x, aR[1]); aW[1] = fmaf(g4.y, ew.y, aW[1]);
                aR[2] = fmaf(g4.z, ew.x, aR[2]); aW[2] = fmaf(g4.z, ew.y, aW[2]);
                aR[3] = fmaf(g4.w, ew.x, aR[3]); aW[3] = fmaf(g4.w, ew.y, aW[3]);
            }
        } else {
            // general gate path: a,c recomputed from global sigma/mu (L2-served)
            int j    = j0 + jl;
            int idx  = (ic * ILEN) * cN + j;
            int eo   = (ic * ILEN) * JT + jl;
            int vo   = (ic * ILEN) * KB;
#pragma unroll 4
            for (int ii = 0; ii < ILEN; ++ii, idx += cN, eo += JT, vo += KB) {
                float sg = sigma[idx];
                float a  = 0.5f / sg;
                float c  = fmaf(-mu[idx], a, 0.5f);
                const float2 ew = ews[eo];
                const float4 v4 = *(const float4*)&stage[vo];
                float g;
                g = clamp01(fmaf(v4.x, a, c)); aR[0] = fmaf(g, ew.x, aR[0]); aW[0] = fmaf(g, ew.y, aW[0]);
                g = clamp01(fmaf(v4.y, a, c)); aR[1] = fmaf(g, ew.x, aR[1]); aW[1] = fmaf(g, ew.y, aW[1]);
                g = clamp01(fmaf(v4.z, a, c)); aR[2] = fmaf(g, ew.x, aR[2]); aW[2] = fmaf(g, ew.y, aW[2]);
                g = clamp01(fmaf(v4.w, a, c)); aR[3] = fmaf(g, ew.x, aR[3]); aW[3] = fmaf(g, ew.y, aW[3]);
            }
        }
        // wave pre-reduce (the wave's two i-chunks, lanes ^32), then 8KB LDS
#pragma unroll
        for (int b = 0; b < KB; ++b) {
            aR[b] += __shfl_xor(aR[b], 32, 64);
            aW[b] += __shfl_xor(aW[b], 32, 64);
        }
        if (lane < JT) {
#pragma unroll
            for (int b = 0; b < KB; ++b) {
                redR[(b * NW + wv_id) * JT + lane] = aR[b];
                redW[(b * NW + wv_id) * JT + lane] = aW[b];
            }
        }
        __syncthreads();

        if (tid < JT * KB) {
            int jj = tid & (JT - 1), bb = tid >> 5;
            float r = 0.f, wv = 0.f;
#pragma unroll
            for (int w = 0; w < NW; ++w) {
                r  += redR[(bb * NW + w) * JT + jj];
                wv += redW[(bb * NW + w) * JT + jj];
            }
            r  += my_srb;
            wv += my_sw;
            float k    = 1.0f / (1.0f + wv);
            float taun = my_tau * k;
            float inv  = 1.0f / (taun + cDELTA);
            float vn   = (taun * inv) * vold + (cDELTA * inv) * k * r;
            if (u == cUNF - 1) {
                vout[my_gidx] = vn;                       // plain: dispatch-end flush
                if (my_mi >= 0) out[my_mi] = fmaf(vn, my_ow, my_ob);
            } else {
                __hip_atomic_store(&vout[my_gidx], vn,
                                   __ATOMIC_RELAXED, __HIP_MEMORY_SCOPE_AGENT);
            }
        }

        if (u < cUNF - 1) {
            __syncthreads();   // vmcnt(0) drain: block's sc1 v-stores at coherence point
            if (tid == 0) {
                __hip_atomic_fetch_add(barU, 1, __ATOMIC_RELAXED, __HIP_MEMORY_SCOPE_AGENT);
                const int target = NJT * (u + 1);   // monotonic counter
                while (__hip_atomic_load(barU, __ATOMIC_RELAXED, __HIP_MEMORY_SCOPE_AGENT) < target)
                    __builtin_amdgcn_s_sleep(1);
            }
            __syncthreads();
            vin = (u & 1) ? vA : vB;   // buffer just produced
        }
    }
}

extern "C" void kernel_launch(void* const* d_in, const int* in_sizes, int n_in,
                              void* d_out, int out_size, void* d_ws, size_t ws_size,
                              hipStream_t stream)
{
    const float* inputs = (const float*)d_in[0];
    const float* states = (const float*)d_in[1];
    const float* tau    = (const float*)d_in[2];
    const float* bias   = (const float*)d_in[3];
    const float* erev   = (const float*)d_in[4];
    const float* wgt    = (const float*)d_in[5];
    const float* sigma  = (const float*)d_in[6];
    const float* mu     = (const float*)d_in[7];
    const float* serev  = (const float*)d_in[8];
    const float* swgt   = (const float*)d_in[9];
    const float* ssigma = (const float*)d_in[10];
    const float* smu    = (const float*)d_in[11];
    const float* mask   = (const float*)d_in[12];
    const float* smask  = (const float*)d_in[13];
    const float* inw    = (const float*)d_in[14];
    const float* inb    = (const float*)d_in[15];
    const float* outw   = (const float*)d_in[16];
    const float* outb   = (const float*)d_in[17];
    float* out = (float*)d_out;
    float* ws  = (float*)d_ws;

    // zero barrier counters + flags
    hipMemsetAsync(ws + OFF_CTR, 0, CTR_INTS * sizeof(int), stream);

    k_prep<<<NB, NT, 0, stream>>>(inputs, bias, erev, wgt, sigma, mu,
                                  serev, swgt, ssigma, smu, mask, smask,
                                  inw, inb, ws);

    // 256 blocks x 1024 threads, 24 KB static LDS -> 1+ block/CU resident;
    // internal spin barriers cannot deadlock.
    k_main<<<NB, NT, 0, stream>>>(states, tau, sigma, mu,
                                  outw, outb, out, ws);
}